// Round 1
// baseline (113.920 us; speedup 1.0000x reference)
//
#include <hip/hip_runtime.h>
#include <math.h>

// STFT -> mag/phase -> ISTFT collapses algebraically to:
//   out[b,i] = input[b,i] * gain[i]
//   gain[i]  = (400/401) * sum_{k=0..3} hann800(r + 200k)   [t-clamped to 0..2400]
// where r = (i+400) % 200, hann800(w) = 0.5 - 0.5*cos(2*pi*w/799).
// Proof sketch: mag*cos(atan2(si,sr)) == sr, mag*sin == si (identity incl. the
// special case); the half-weighted trapezoidal iDFT kernel is exactly
// 400*delta[d mod 800] so contrib = (400/401)*win*frame; overlap-add of the
// window then multiplies each padded sample; the [PAD:-PAD] crop keeps only
// samples where x_pad == input (reflect pad never reaches the output).

#define T_OUT   480000
#define NBATCH  32
#define PADK    400
#define HOPK    200
#define NFRAMES 2401
#define GAIN_SCALE 0.9975062344139651f   // 400/401

__device__ __forceinline__ float hann800(int w) {
    // np.hanning(800)[w] = 0.5 - 0.5*cos(2*pi*w/799)
    const float c = 6.2831853071795864769f / 799.0f;
    return 0.5f - 0.5f * cosf(c * (float)w);
}

__device__ __forceinline__ float gain_at(int i) {
    int n = i + PADK;
    int r = n % HOPK;
    float g = 0.0f;
#pragma unroll
    for (int k = 0; k < 4; ++k) {
        int w = r + HOPK * k;
        int t = (n - w) / HOPK;           // exact: (n-w) is a multiple of 200
        if (t >= 0 && t < NFRAMES)
            g += hann800(w);
    }
    return g * GAIN_SCALE;
}

__global__ void build_gain_kernel(float* __restrict__ gain) {
    int i = blockIdx.x * blockDim.x + threadIdx.x;
    if (i < T_OUT)
        gain[i] = gain_at(i);
}

__global__ void scale_kernel(const float4* __restrict__ in,
                             const float4* __restrict__ gain,
                             float4* __restrict__ out) {
    int i4 = blockIdx.x * blockDim.x + threadIdx.x;   // float4 index within a row
    if (i4 >= T_OUT / 4) return;
    size_t idx = (size_t)blockIdx.y * (T_OUT / 4) + i4;
    float4 x = in[idx];
    float4 g = gain[i4];
    float4 o;
    o.x = x.x * g.x;
    o.y = x.y * g.y;
    o.z = x.z * g.z;
    o.w = x.w * g.w;
    out[idx] = o;
}

// Fallback if workspace is too small: compute gain inline (more VALU, still correct).
__global__ void scale_inline_kernel(const float4* __restrict__ in,
                                    float4* __restrict__ out) {
    int i4 = blockIdx.x * blockDim.x + threadIdx.x;
    if (i4 >= T_OUT / 4) return;
    size_t idx = (size_t)blockIdx.y * (T_OUT / 4) + i4;
    int i = i4 * 4;
    float4 x = in[idx];
    float4 o;
    o.x = x.x * gain_at(i + 0);
    o.y = x.y * gain_at(i + 1);
    o.z = x.z * gain_at(i + 2);
    o.w = x.w * gain_at(i + 3);
    out[idx] = o;
}

extern "C" void kernel_launch(void* const* d_in, const int* in_sizes, int n_in,
                              void* d_out, int out_size, void* d_ws, size_t ws_size,
                              hipStream_t stream) {
    const float* in = (const float*)d_in[0];
    float* out = (float*)d_out;

    const int row4 = T_OUT / 4;                 // 120000 float4 per row
    dim3 block(256);
    dim3 grid((row4 + 255) / 256, NBATCH);      // (469, 32)

    if (ws_size >= (size_t)T_OUT * sizeof(float)) {
        float* gain = (float*)d_ws;
        build_gain_kernel<<<dim3((T_OUT + 255) / 256), block, 0, stream>>>(gain);
        scale_kernel<<<grid, block, 0, stream>>>(
            (const float4*)in, (const float4*)gain, (float4*)out);
    } else {
        scale_inline_kernel<<<grid, block, 0, stream>>>(
            (const float4*)in, (float4*)out);
    }
}